// Round 2
// baseline (299.359 us; speedup 1.0000x reference)
//
#include <hip/hip_runtime.h>

#define B_   16
#define CIN  32
#define COUT 32
#define HH   256
#define WW   256
#define NE   8
#define NTAP 9
#define KTOT (NTAP * CIN)   // 288

#define TH 8
#define TW 32
#define LROWS (TH + 2)      // 10
#define LCOLS (TW + 2)      // 34
#define PXS   40            // ushorts per pixel: 32 data + 8 pad = 80 B (bank group 5p+quad, bijective mod 8)

typedef __attribute__((ext_vector_type(8))) short  short8;   // 8 bf16 = 4 VGPRs
typedef __attribute__((ext_vector_type(4))) float  floatx4;  // MFMA C/D

// fp32 -> bf16, round-to-nearest-even
__device__ __forceinline__ unsigned short f2bf(float f) {
    unsigned int u = __float_as_uint(f);
    u += 0x7FFFu + ((u >> 16) & 1u);
    return (unsigned short)(u >> 16);
}

// ---------------------------------------------------------------------------
// Mix expert weights per sample -> bf16, layout [b][co][k = tap*32 + ci].
// Reference weight flat index: co*288 + ci*9 + tap.
// ---------------------------------------------------------------------------
__global__ __launch_bounds__(256) void prep_weights(
    const float* __restrict__ routing,   // [16][8]
    const float* __restrict__ ew,        // [8][9216]
    const float* __restrict__ eb,        // [8][32]
    unsigned short* __restrict__ ws_w,   // [16][32][288] bf16 bits
    float* __restrict__ ws_b)            // [16][32]
{
    const int b = blockIdx.x;
    const int t = threadIdx.x;
    float r[NE];
#pragma unroll
    for (int e = 0; e < NE; ++e) r[e] = routing[b * NE + e];

    for (int idx = t; idx < COUT * KTOT; idx += 256) {
        const int co  = idx / KTOT;
        const int k   = idx - co * KTOT;
        const int tap = k >> 5;          // k / 32
        const int ci  = k & 31;
        float acc = 0.f;
#pragma unroll
        for (int e = 0; e < NE; ++e)
            acc += r[e] * ew[e * (COUT * CIN * 9) + co * (CIN * 9) + ci * 9 + tap];
        ws_w[(b * COUT + co) * KTOT + k] = f2bf(acc);
    }
    if (t < COUT) {
        float acc = 0.f;
#pragma unroll
        for (int e = 0; e < NE; ++e) acc += r[e] * eb[e * COUT + t];
        ws_b[b * COUT + t] = acc;
    }
}

// ---------------------------------------------------------------------------
// Implicit-GEMM conv. Block = 256 thr (4 waves), one 8x32 output tile / batch.
// Occupancy-first layout: LDS 27.2 KB (5 blocks/CU), acc[4][2] (32 regs),
// weights NOT preloaded: rolled tap loop with 2-tap register double-buffer
// (weight reloads are L1-hot: 18.4 KB per batch).
// ---------------------------------------------------------------------------
__global__ __launch_bounds__(256, 4) void condconv_mfma(
    const float* __restrict__ x,             // [16][32][256][256] fp32
    const unsigned short* __restrict__ wsw,  // [16][32][288] bf16
    const float* __restrict__ wsb,           // [16][32]
    float* __restrict__ out)                 // [16][32][256][256] fp32
{
    __shared__ __align__(16) unsigned short s_x[LROWS * LCOLS * PXS];  // 27.2 KB

    const int b    = blockIdx.z;
    const int x0   = blockIdx.x * TW;
    const int y0   = blockIdx.y * TH;
    const int t    = threadIdx.x;
    const int lane = t & 63;
    const int wv   = t >> 6;        // wave 0..3
    const int ln   = lane & 15;     // MFMA n / m-within-half
    const int quad = lane >> 4;     // MFMA k-group / row-group

    // --- stage input tile: fp32 NCHW global -> bf16 [pixel][ci] LDS ---
    // task = pixel * 4 + ci_chunk; each task: 8 coalesced plane reads -> 1 b128 write
    for (int task = t; task < LROWS * LCOLS * 4; task += 256) {
        const int p   = task >> 2;
        const int c   = task & 3;
        const int row = p / LCOLS;
        const int col = p - row * LCOLS;
        const int gy  = y0 + row - 1;
        const int gx  = x0 + col - 1;
        short8 pk;
        if (gy >= 0 && gy < HH && gx >= 0 && gx < WW) {
            const float* src = x + (((size_t)b * CIN + c * 8) * HH + gy) * WW + gx;
#pragma unroll
            for (int u = 0; u < 8; ++u)
                pk[u] = (short)f2bf(src[(size_t)u * HH * WW]);
        } else {
#pragma unroll
            for (int u = 0; u < 8; ++u) pk[u] = 0;
        }
        *(short8*)&s_x[p * PXS + c * 8] = pk;
    }

    // --- first A fragments (tap 0) while staging drains ---
    const unsigned short* wb = wsw + (size_t)b * COUT * KTOT;
    short8 afc0 = *(const short8*)(wb + ln * KTOT + quad * 8);
    short8 afc1 = *(const short8*)(wb + (16 + ln) * KTOT + quad * 8);

    floatx4 acc[4][2];
#pragma unroll
    for (int tt = 0; tt < 4; ++tt)
#pragma unroll
        for (int h = 0; h < 2; ++h)
            acc[tt][h] = (floatx4){0.f, 0.f, 0.f, 0.f};

    // per-subtile LDS base (ushort units): subtile tt = (dr<<1)|q
    int base[4];
#pragma unroll
    for (int tt = 0; tt < 4; ++tt)
        base[tt] = ((2 * wv + (tt >> 1)) * LCOLS + (tt & 1) * 16 + ln) * PXS + quad * 8;

    __syncthreads();

    // --- K loop: 9 taps, rolled; prefetch next tap's A frags (L1-hot) ---
#pragma unroll 1
    for (int tap = 0; tap < NTAP; ++tap) {
        const int tn = (tap < NTAP - 1) ? tap + 1 : NTAP - 1;
        const short8 afn0 = *(const short8*)(wb + ln * KTOT + tn * 32 + quad * 8);
        const short8 afn1 = *(const short8*)(wb + (16 + ln) * KTOT + tn * 32 + quad * 8);
        const int dy  = tap / 3;
        const int dx  = tap - dy * 3;
        const int off = (dy * LCOLS + dx) * PXS;   // wave-uniform
#pragma unroll
        for (int tt = 0; tt < 4; ++tt) {
            const short8 bfr = *(const short8*)&s_x[base[tt] + off];
            acc[tt][0] = __builtin_amdgcn_mfma_f32_16x16x32_bf16(afc0, bfr, acc[tt][0], 0, 0, 0);
            acc[tt][1] = __builtin_amdgcn_mfma_f32_16x16x32_bf16(afc1, bfr, acc[tt][1], 0, 0, 0);
        }
        afc0 = afn0;
        afc1 = afn1;
    }

    // --- epilogue: bias + coalesced (64B-segment) stores ---
    float bias_v[2][4];
#pragma unroll
    for (int h = 0; h < 2; ++h)
#pragma unroll
        for (int rg = 0; rg < 4; ++rg)
            bias_v[h][rg] = wsb[b * COUT + h * 16 + quad * 4 + rg];

#pragma unroll
    for (int tt = 0; tt < 4; ++tt) {
        const int r  = 2 * wv + (tt >> 1);
        const int q  = tt & 1;
        const int gy = y0 + r;
        const int gx = x0 + q * 16 + ln;
#pragma unroll
        for (int h = 0; h < 2; ++h)
#pragma unroll
            for (int rg = 0; rg < 4; ++rg) {
                const int co = h * 16 + quad * 4 + rg;
                out[(((size_t)b * COUT + co) * HH + gy) * WW + gx] = acc[tt][h][rg] + bias_v[h][rg];
            }
    }
}

extern "C" void kernel_launch(void* const* d_in, const int* in_sizes, int n_in,
                              void* d_out, int out_size, void* d_ws, size_t ws_size,
                              hipStream_t stream) {
    const float* x       = (const float*)d_in[0];
    const float* routing = (const float*)d_in[1];
    const float* ew      = (const float*)d_in[2];
    const float* eb      = (const float*)d_in[3];
    float* out = (float*)d_out;

    unsigned short* ws_w = (unsigned short*)d_ws;            // 16*32*288 bf16 = 294912 B
    float* ws_b = (float*)((char*)d_ws + (size_t)B_ * COUT * KTOT * 2);

    prep_weights<<<dim3(B_), dim3(256), 0, stream>>>(routing, ew, eb, ws_w, ws_b);

    dim3 grid(WW / TW, HH / TH, B_);                         // (8, 32, 16)
    condconv_mfma<<<grid, dim3(256), 0, stream>>>(x, ws_w, ws_b, out);
}

// Round 3
// 287.160 us; speedup vs baseline: 1.0425x; 1.0425x over previous
//
#include <hip/hip_runtime.h>

#define B_   16
#define CIN  32
#define COUT 32
#define HH   256
#define WW   256
#define NE   8
#define NTAP 9
#define KTOT (NTAP * CIN)   // 288

#define TH 8
#define TW 64
#define LROWS (TH + 2)      // 10
#define LCOLS (TW + 2)      // 66
#define PXS   40            // ushorts per pixel: 32 data + 8 pad = 80 B (bank spread)
#define NI    ((TW + 8) / 4) // 18 aligned float4 positions per halo row

typedef __attribute__((ext_vector_type(8))) short  short8;   // 8 bf16 = 4 VGPRs
typedef __attribute__((ext_vector_type(4))) float  floatx4;  // MFMA C/D + vec loads

// fp32 -> bf16, round-to-nearest-even
__device__ __forceinline__ unsigned short f2bf(float f) {
    unsigned int u = __float_as_uint(f);
    u += 0x7FFFu + ((u >> 16) & 1u);
    return (unsigned short)(u >> 16);
}

// ---------------------------------------------------------------------------
// Mix expert weights per sample -> bf16, layout [b][co][k = tap*32 + ci].
// Reference weight flat index: co*288 + ci*9 + tap.
// ---------------------------------------------------------------------------
__global__ __launch_bounds__(256) void prep_weights(
    const float* __restrict__ routing,   // [16][8]
    const float* __restrict__ ew,        // [8][9216]
    const float* __restrict__ eb,        // [8][32]
    unsigned short* __restrict__ ws_w,   // [16][32][288] bf16 bits
    float* __restrict__ ws_b)            // [16][32]
{
    const int b = blockIdx.x;
    const int t = threadIdx.x;
    float r[NE];
#pragma unroll
    for (int e = 0; e < NE; ++e) r[e] = routing[b * NE + e];

    for (int idx = t; idx < COUT * KTOT; idx += 256) {
        const int co  = idx / KTOT;
        const int k   = idx - co * KTOT;
        const int tap = k >> 5;          // k / 32
        const int ci  = k & 31;
        float acc = 0.f;
#pragma unroll
        for (int e = 0; e < NE; ++e)
            acc += r[e] * ew[e * (COUT * CIN * 9) + co * (CIN * 9) + ci * 9 + tap];
        ws_w[(b * COUT + co) * KTOT + k] = f2bf(acc);
    }
    if (t < COUT) {
        float acc = 0.f;
#pragma unroll
        for (int e = 0; e < NE; ++e) acc += r[e] * eb[e * COUT + t];
        ws_b[b * COUT + t] = acc;
    }
}

// ---------------------------------------------------------------------------
// Implicit-GEMM conv. Block = 256 thr (4 waves), one 8x64 output tile / batch.
// Staging is READ-vectorized: each task loads 8 planes x 4 consecutive pixels
// via aligned global_load_dwordx4 (16 B/lane), transposes in registers, and
// writes 4 pixels' 8-channel chunks as ds_write_b128. Rolled tap loop keeps
// VGPRs low; weight reloads are L1-hot (18.4 KB/batch).
// ---------------------------------------------------------------------------
__global__ __launch_bounds__(256, 3) void condconv_mfma(
    const float* __restrict__ x,             // [16][32][256][256] fp32
    const unsigned short* __restrict__ wsw,  // [16][32][288] bf16
    const float* __restrict__ wsb,           // [16][32]
    float* __restrict__ out)                 // [16][32][256][256] fp32
{
    __shared__ __align__(16) unsigned short s_x[LROWS * LCOLS * PXS];  // 52.8 KB

    const int b    = blockIdx.z;
    const int x0   = blockIdx.x * TW;
    const int y0   = blockIdx.y * TH;
    const int t    = threadIdx.x;
    const int lane = t & 63;
    const int wv   = t >> 6;        // wave 0..3
    const int ln   = lane & 15;     // MFMA n / m-within-half
    const int quad = lane >> 4;     // MFMA k-group / row-group

    // --- stage input tile: aligned float4 reads -> register transpose -> b128 LDS writes ---
    // task = (row * NI + i) * 4 + cgroup; float4 span gx = x0-4+4i is always
    // fully inside or fully outside the image horizontally (WW % 4 == 0).
    for (int task = t; task < LROWS * NI * 4; task += 256) {   // 720 tasks
        const int cg  = task & 3;
        const int ri  = task >> 2;
        const int i   = ri % NI;
        const int row = ri / NI;
        const int gy  = y0 + row - 1;
        const int gx  = x0 + 4 * i - 4;
        floatx4 v[8];
        if (gy >= 0 && gy < HH && gx >= 0 && gx < WW) {
            const float* src = x + (((size_t)b * CIN + cg * 8) * HH + gy) * WW + gx;
#pragma unroll
            for (int u = 0; u < 8; ++u)
                v[u] = *(const floatx4*)(src + (size_t)u * HH * WW);
        } else {
#pragma unroll
            for (int u = 0; u < 8; ++u) v[u] = (floatx4){0.f, 0.f, 0.f, 0.f};
        }
#pragma unroll
        for (int j = 0; j < 4; ++j) {
            const int lcol = 4 * i + j - 3;
            if (lcol >= 0 && lcol < LCOLS) {
                short8 pk;
#pragma unroll
                for (int u = 0; u < 8; ++u) pk[u] = (short)f2bf(v[u][j]);
                *(short8*)&s_x[(row * LCOLS + lcol) * PXS + cg * 8] = pk;
            }
        }
    }

    // --- first A fragments (tap 0) while staging drains ---
    const unsigned short* wb = wsw + (size_t)b * COUT * KTOT;
    short8 afc0 = *(const short8*)(wb + ln * KTOT + quad * 8);
    short8 afc1 = *(const short8*)(wb + (16 + ln) * KTOT + quad * 8);

    floatx4 acc[8][2];
#pragma unroll
    for (int tt = 0; tt < 8; ++tt)
#pragma unroll
        for (int h = 0; h < 2; ++h)
            acc[tt][h] = (floatx4){0.f, 0.f, 0.f, 0.f};

    // per-subtile LDS base (ushort units): subtile tt -> row 2*wv+(tt>>2), col (tt&3)*16+ln
    int base[8];
#pragma unroll
    for (int tt = 0; tt < 8; ++tt)
        base[tt] = ((2 * wv + (tt >> 2)) * LCOLS + (tt & 3) * 16 + ln) * PXS + quad * 8;

    __syncthreads();

    // --- K loop: 9 taps, rolled; prefetch next tap's A frags (L1-hot) ---
#pragma unroll 1
    for (int tap = 0; tap < NTAP; ++tap) {
        const int tn = (tap < NTAP - 1) ? tap + 1 : NTAP - 1;
        const short8 afn0 = *(const short8*)(wb + ln * KTOT + tn * 32 + quad * 8);
        const short8 afn1 = *(const short8*)(wb + (16 + ln) * KTOT + tn * 32 + quad * 8);
        const int dy  = tap / 3;
        const int dx  = tap - dy * 3;
        const int off = (dy * LCOLS + dx) * PXS;   // wave-uniform
#pragma unroll
        for (int tt = 0; tt < 8; ++tt) {
            const short8 bfr = *(const short8*)&s_x[base[tt] + off];
            acc[tt][0] = __builtin_amdgcn_mfma_f32_16x16x32_bf16(afc0, bfr, acc[tt][0], 0, 0, 0);
            acc[tt][1] = __builtin_amdgcn_mfma_f32_16x16x32_bf16(afc1, bfr, acc[tt][1], 0, 0, 0);
        }
        afc0 = afn0;
        afc1 = afn1;
    }

    // --- epilogue: bias + coalesced (64B-segment) stores ---
    float bias_v[2][4];
#pragma unroll
    for (int h = 0; h < 2; ++h)
#pragma unroll
        for (int rg = 0; rg < 4; ++rg)
            bias_v[h][rg] = wsb[b * COUT + h * 16 + quad * 4 + rg];

#pragma unroll
    for (int tt = 0; tt < 8; ++tt) {
        const int r  = 2 * wv + (tt >> 2);
        const int q  = tt & 3;
        const int gy = y0 + r;
        const int gx = x0 + q * 16 + ln;
#pragma unroll
        for (int h = 0; h < 2; ++h)
#pragma unroll
            for (int rg = 0; rg < 4; ++rg) {
                const int co = h * 16 + quad * 4 + rg;
                out[(((size_t)b * COUT + co) * HH + gy) * WW + gx] = acc[tt][h][rg] + bias_v[h][rg];
            }
    }
}

extern "C" void kernel_launch(void* const* d_in, const int* in_sizes, int n_in,
                              void* d_out, int out_size, void* d_ws, size_t ws_size,
                              hipStream_t stream) {
    const float* x       = (const float*)d_in[0];
    const float* routing = (const float*)d_in[1];
    const float* ew      = (const float*)d_in[2];
    const float* eb      = (const float*)d_in[3];
    float* out = (float*)d_out;

    unsigned short* ws_w = (unsigned short*)d_ws;            // 16*32*288 bf16 = 294912 B
    float* ws_b = (float*)((char*)d_ws + (size_t)B_ * COUT * KTOT * 2);

    prep_weights<<<dim3(B_), dim3(256), 0, stream>>>(routing, ew, eb, ws_w, ws_b);

    dim3 grid(WW / TW, HH / TH, B_);                         // (4, 32, 16)
    condconv_mfma<<<grid, dim3(256), 0, stream>>>(x, ws_w, ws_b, out);
}